// Round 5
// baseline (619.780 us; speedup 1.0000x reference)
//
#include <hip/hip_runtime.h>
#include <hip/hip_bf16.h>
#include <math.h>

typedef __bf16 bf16_t;
typedef bf16_t bf16x8 __attribute__((ext_vector_type(8)));
typedef float  f32x4  __attribute__((ext_vector_type(4)));

static constexpr int Bn = 16384;
static constexpr int Hn = 512;

__device__ __forceinline__ float sigm(float x) { return 1.0f / (1.0f + __expf(-x)); }

typedef __attribute__((address_space(3))) void lds_void;
typedef const __attribute__((address_space(1))) void gl_void;

__device__ __forceinline__ void glds16(const void* g, void* l) {
    __builtin_amdgcn_global_load_lds((gl_void*)g, (lds_void*)l, 16, 0, 0);
}

// comb[B][1024] bf16 = [input | hidden]
__global__ void convert_comb(const float* __restrict__ inp, const float* __restrict__ hid,
                             bf16_t* __restrict__ comb)
{
    size_t t = (size_t)blockIdx.x * blockDim.x + threadIdx.x;
    size_t r = t >> 7;
    int c8 = (int)(t & 127);
    const float* src = (c8 < 64) ? (inp + r * 512 + c8 * 8) : (hid + r * 512 + (c8 - 64) * 8);
    float4 a = ((const float4*)src)[0];
    float4 b = ((const float4*)src)[1];
    bf16x8 o;
    o[0] = (bf16_t)a.x; o[1] = (bf16_t)a.y; o[2] = (bf16_t)a.z; o[3] = (bf16_t)a.w;
    o[4] = (bf16_t)b.x; o[5] = (bf16_t)b.y; o[6] = (bf16_t)b.z; o[7] = (bf16_t)b.w;
    *(bf16x8*)(comb + t * 8) = o;
}

// All three weight transposes in one launch.
__global__ void transpose_all(const float* __restrict__ Wg, bf16_t* __restrict__ WgT,
                              const float* __restrict__ Wa, bf16_t* __restrict__ WaT,
                              const float* __restrict__ Mem, bf16_t* __restrict__ MemT)
{
    __shared__ float tile[32][33];
    int b = blockIdx.x;
    const float* src; bf16_t* dst; int R, C, gx;
    if (b < 2048)      { src = Wg;  dst = WgT;  R = 1024; C = 2048; gx = 64; }
    else if (b < 4096) { b -= 2048; src = Wa;  dst = WaT;  R = 512;  C = 4096; gx = 128; }
    else               { b -= 4096; src = Mem; dst = MemT; R = 4096; C = 512;  gx = 16; }
    const int x0 = (b % gx) * 32, y0 = (b / gx) * 32;
    const int tx = threadIdx.x & 31, ty = threadIdx.x >> 5;
#pragma unroll
    for (int i = 0; i < 32; i += 8)
        tile[ty + i][tx] = src[(size_t)(y0 + ty + i) * C + x0 + tx];
    __syncthreads();
#pragma unroll
    for (int i = 0; i < 32; i += 8)
        dst[(size_t)(x0 + ty + i) * R + y0 + tx] = (bf16_t)tile[tx][ty + i];
}

// Fused gates+logits GEMM. Grid 6144 = 128 rowblocks x 48 colblocks.
// colblock < 16: gates (K=1024, WgT, bg). colblock >= 16: logits (K=512, WaT, ba).
// 128x128 tile, BK=64, 4 waves 2x2; LDS rows 128B, 16B-slot swizzle s ^= (row&7).
__global__ __launch_bounds__(256)
void gemm12(const bf16_t* __restrict__ comb,
            const bf16_t* __restrict__ WgT, const bf16_t* __restrict__ WaT,
            const float* __restrict__ bg, const float* __restrict__ ba,
            bf16_t* __restrict__ gates, bf16_t* __restrict__ logit, int lstride)
{
    __shared__ __align__(16) bf16_t sA[128 * 64];
    __shared__ __align__(16) bf16_t sB[128 * 64];

    const int tid = threadIdx.x, lane = tid & 63, wid = tid >> 6;
    const int wr = wid >> 1, wc = wid & 1;

    int bid = (blockIdx.x & 7) * 768 + (blockIdx.x >> 3);   // bijective XCD swizzle
    const int rb = bid / 48, cb = bid % 48;
    const bool g = cb < 16;
    const int K = g ? 1024 : 512;
    const bf16_t* A  = comb + (g ? 0 : 512);
    const bf16_t* Bt = g ? WgT : WaT;                       // ldb == K for both
    const int col0 = (g ? cb : cb - 16) * 128;
    const int row0 = rb * 128;

    f32x4 acc[4][4] = {};
    const int nk = K >> 6;
    const int l15 = lane & 15, kq = lane >> 4;

    for (int kt = 0; kt < nk; ++kt) {
        const int k0 = kt << 6;
#pragma unroll
        for (int t = 0; t < 4; ++t) {
            const int c8 = wid * 4 + t;
            const int r = c8 * 8 + (lane >> 3);
            const int slot = (lane & 7) ^ (lane >> 3);
            glds16(A + (size_t)(row0 + r) * 1024 + k0 + slot * 8, sA + c8 * 512);
            glds16(Bt + (size_t)(col0 + r) * K + k0 + slot * 8, sB + c8 * 512);
        }
        __syncthreads();
#pragma unroll
        for (int ks = 0; ks < 2; ++ks) {
            bf16x8 af[4], bfr[4];
#pragma unroll
            for (int j = 0; j < 4; ++j) {
                const int rbq = wc * 64 + j * 16 + l15;
                const int slot = (ks * 4 + kq) ^ (l15 & 7);
                bfr[j] = *(const bf16x8*)&sB[rbq * 64 + slot * 8];
                const int ra = wr * 64 + j * 16 + l15;
                af[j] = *(const bf16x8*)&sA[ra * 64 + slot * 8];
            }
#pragma unroll
            for (int i = 0; i < 4; ++i)
#pragma unroll
                for (int j = 0; j < 4; ++j)
                    acc[i][j] = __builtin_amdgcn_mfma_f32_16x16x32_bf16(af[i], bfr[j], acc[i][j], 0, 0, 0);
        }
        __syncthreads();
    }

    const int lr = (lane >> 4) * 4, lc = lane & 15;
#pragma unroll
    for (int i = 0; i < 4; ++i) {
#pragma unroll
        for (int j = 0; j < 4; ++j) {
#pragma unroll
            for (int r = 0; r < 4; ++r) {
                const int grow = row0 + wr * 64 + i * 16 + lr + r;
                const int gcol = col0 + wc * 64 + j * 16 + lc;
                float v = acc[i][j][r];
                if (g) {
                    v += bg[gcol];
                    const float a = ((gcol >> 9) == 2) ? tanhf(v) : sigm(v);
                    gates[(size_t)grow * 2048 + gcol] = (bf16_t)a;
                } else {
                    logit[(size_t)grow * lstride + gcol] = (bf16_t)(v + ba[gcol]);
                }
            }
        }
    }
}

// mr = attn_bf16 @ MemT^T fused with LSTM update. Tile 64x128, BK=64, 4 waves 2x2.
__global__ __launch_bounds__(256)
void gemm3k(const bf16_t* __restrict__ Ap, int astride,
            const bf16_t* __restrict__ MemT,
            const bf16_t* __restrict__ gates, const float* __restrict__ cell,
            float* __restrict__ fout)
{
    __shared__ __align__(16) bf16_t sA[64 * 64];
    __shared__ __align__(16) bf16_t sB[128 * 64];

    const int tid = threadIdx.x, lane = tid & 63, wid = tid >> 6;
    const int wr = wid >> 1, wc = wid & 1;

    int bid = (blockIdx.x & 7) * 128 + (blockIdx.x >> 3);   // 1024 blocks
    const int row0 = (bid >> 2) * 64, col0 = (bid & 3) * 128;

    f32x4 acc[2][4] = {};
    const int l15 = lane & 15, kq = lane >> 4;

    for (int kt = 0; kt < 64; ++kt) {
        const int k0 = kt << 6;
#pragma unroll
        for (int t = 0; t < 2; ++t) {                        // A: 8 chunks (64 rows)
            const int c8 = wid * 2 + t;
            const int r = c8 * 8 + (lane >> 3);
            const int slot = (lane & 7) ^ (lane >> 3);
            glds16(Ap + (size_t)(row0 + r) * astride + k0 + slot * 8, sA + c8 * 512);
        }
#pragma unroll
        for (int t = 0; t < 4; ++t) {                        // B: 16 chunks (128 rows)
            const int c8 = wid * 4 + t;
            const int r = c8 * 8 + (lane >> 3);
            const int slot = (lane & 7) ^ (lane >> 3);
            glds16(MemT + (size_t)(col0 + r) * 4096 + k0 + slot * 8, sB + c8 * 512);
        }
        __syncthreads();
#pragma unroll
        for (int ks = 0; ks < 2; ++ks) {
            bf16x8 af[2], bfr[4];
#pragma unroll
            for (int j = 0; j < 4; ++j) {
                const int rbq = wc * 64 + j * 16 + l15;
                const int slot = (ks * 4 + kq) ^ (l15 & 7);
                bfr[j] = *(const bf16x8*)&sB[rbq * 64 + slot * 8];
            }
#pragma unroll
            for (int i = 0; i < 2; ++i) {
                const int ra = wr * 32 + i * 16 + l15;
                const int slot = (ks * 4 + kq) ^ (l15 & 7);
                af[i] = *(const bf16x8*)&sA[ra * 64 + slot * 8];
            }
#pragma unroll
            for (int i = 0; i < 2; ++i)
#pragma unroll
                for (int j = 0; j < 4; ++j)
                    acc[i][j] = __builtin_amdgcn_mfma_f32_16x16x32_bf16(af[i], bfr[j], acc[i][j], 0, 0, 0);
        }
        __syncthreads();
    }

    const int lr = (lane >> 4) * 4, lc = lane & 15;
#pragma unroll
    for (int i = 0; i < 2; ++i) {
#pragma unroll
        for (int j = 0; j < 4; ++j) {
#pragma unroll
            for (int r = 0; r < 4; ++r) {
                const int grow = row0 + wr * 32 + i * 16 + lr + r;
                const int gcol = col0 + wc * 64 + j * 16 + lc;
                const float v = acc[i][j][r];
                const float ig = (float)gates[(size_t)grow * 2048 + gcol];
                const float fg = (float)gates[(size_t)grow * 2048 + 512 + gcol];
                const float cg = (float)gates[(size_t)grow * 2048 + 1024 + gcol];
                const float og = (float)gates[(size_t)grow * 2048 + 1536 + gcol];
                const float cv = cell[(size_t)grow * 512 + gcol];
                const float ncv = fg * cv + ig * cg + 0.1f * v;
                fout[(size_t)grow * 512 + gcol] = og * tanhf(ncv);
                fout[(size_t)Bn * Hn + (size_t)grow * 512 + gcol] = ncv;
            }
        }
    }
}

// Row softmax over packed bf16 logits (stride pstride bf16/row). Writes bf16 attn back
// in place; if F32OUT also writes the full fp32 attn row to attnf32.
template<bool F32OUT>
__global__ void softmax_k(bf16_t* __restrict__ packed, int pstride, float* __restrict__ attnf32)
{
    const int row = blockIdx.x;
    bf16_t* lp = packed + (size_t)row * pstride;
    const int tid = threadIdx.x;

    float v[16];
    {
        bf16x8 h0 = ((const bf16x8*)lp)[tid];
        bf16x8 h1 = ((const bf16x8*)lp)[tid + 256];
#pragma unroll
        for (int k = 0; k < 8; ++k) { v[k] = (float)h0[k]; v[8 + k] = (float)h1[k]; }
    }
    float mx = v[0];
#pragma unroll
    for (int k = 1; k < 16; ++k) mx = fmaxf(mx, v[k]);
#pragma unroll
    for (int off = 32; off > 0; off >>= 1) mx = fmaxf(mx, __shfl_xor(mx, off));
    __shared__ float smx[4], ssm[4];
    if ((tid & 63) == 0) smx[tid >> 6] = mx;
    __syncthreads();
    mx = fmaxf(fmaxf(smx[0], smx[1]), fmaxf(smx[2], smx[3]));

    float sum = 0.0f;
#pragma unroll
    for (int k = 0; k < 16; ++k) { v[k] = __expf(v[k] - mx); sum += v[k]; }
#pragma unroll
    for (int off = 32; off > 0; off >>= 1) sum += __shfl_xor(sum, off);
    if ((tid & 63) == 0) ssm[tid >> 6] = sum;
    __syncthreads();
    sum = ssm[0] + ssm[1] + ssm[2] + ssm[3];

    const float inv = 1.0f / sum;
#pragma unroll
    for (int k = 0; k < 16; ++k) v[k] *= inv;

    bf16x8 o0, o1;
#pragma unroll
    for (int k = 0; k < 8; ++k) { o0[k] = (bf16_t)v[k]; o1[k] = (bf16_t)v[8 + k]; }
    ((bf16x8*)lp)[tid]       = o0;
    ((bf16x8*)lp)[tid + 256] = o1;

    if constexpr (F32OUT) {
        float* rp = attnf32 + (size_t)row * 4096;
        float4 a0 = { v[0], v[1], v[2], v[3] },   a1 = { v[4], v[5], v[6], v[7] };
        float4 a2 = { v[8], v[9], v[10], v[11] }, a3 = { v[12], v[13], v[14], v[15] };
        ((float4*)rp)[2 * tid]             = a0;
        ((float4*)rp)[2 * tid + 1]         = a1;
        ((float4*)rp)[2 * (tid + 256)]     = a2;
        ((float4*)rp)[2 * (tid + 256) + 1] = a3;
    }
}

// Expand packed bf16 attn row (first half) -> full fp32 row, in place (fallback path).
__global__ void expand_attn(float* __restrict__ attn)
{
    const int row = blockIdx.x;
    float* rp = attn + (size_t)row * 4096;
    const int t = threadIdx.x;
    bf16x8 h0 = ((const bf16x8*)rp)[2 * t];
    bf16x8 h1 = ((const bf16x8*)rp)[2 * t + 1];
    __syncthreads();
    float4 o0 = { (float)h0[0], (float)h0[1], (float)h0[2], (float)h0[3] };
    float4 o1 = { (float)h0[4], (float)h0[5], (float)h0[6], (float)h0[7] };
    float4 o2 = { (float)h1[0], (float)h1[1], (float)h1[2], (float)h1[3] };
    float4 o3 = { (float)h1[4], (float)h1[5], (float)h1[6], (float)h1[7] };
    ((float4*)rp)[4 * t]     = o0;
    ((float4*)rp)[4 * t + 1] = o1;
    ((float4*)rp)[4 * t + 2] = o2;
    ((float4*)rp)[4 * t + 3] = o3;
}

extern "C" void kernel_launch(void* const* d_in, const int* in_sizes, int n_in,
                              void* d_out, int out_size, void* d_ws, size_t ws_size,
                              hipStream_t stream)
{
    const float* input  = (const float*)d_in[0];
    const float* hidden = (const float*)d_in[1];
    const float* cell   = (const float*)d_in[2];
    const float* Wg     = (const float*)d_in[3];
    const float* bg     = (const float*)d_in[4];
    const float* Wa     = (const float*)d_in[5];
    const float* ba     = (const float*)d_in[6];
    const float* Mem    = (const float*)d_in[7];

    float* out  = (float*)d_out;
    float* attn = out + 2ull * Bn * Hn;

    bf16_t* comb  = (bf16_t*)d_ws;                 // [B][1024]      33.5 MB
    bf16_t* WgT   = comb + (size_t)Bn * 1024;      // [2048][1024]    4.2
    bf16_t* WaT   = WgT + (size_t)2048 * 1024;     // [4096][512]     4.2
    bf16_t* MemT  = WaT + (size_t)4096 * 512;      // [512][4096]     4.2
    bf16_t* gates = MemT + (size_t)512 * 4096;     // [B][2048]      67.1
    bf16_t* pws   = gates + (size_t)Bn * 2048;     // [B][4096]     134.2 (big path)

    const size_t need_big = ((size_t)Bn * 1024 + 2048 * 1024 + 4096 * 512 + 512 * 4096
                             + (size_t)Bn * 2048 + (size_t)Bn * 4096) * sizeof(bf16_t);
    const bool big = ws_size >= need_big;
    bf16_t* packed = big ? pws : (bf16_t*)attn;
    const int pstride = big ? 4096 : 8192;

    convert_comb<<<8192, 256, 0, stream>>>(input, hidden, comb);
    transpose_all<<<6144, 256, 0, stream>>>(Wg, WgT, Wa, WaT, Mem, MemT);

    // gates + logits in one launch
    gemm12<<<6144, 256, 0, stream>>>(comb, WgT, WaT, bg, ba, gates, packed, pstride);

    if (big) softmax_k<true><<<Bn, 256, 0, stream>>>(packed, pstride, attn);
    else     softmax_k<false><<<Bn, 256, 0, stream>>>(packed, pstride, nullptr);

    // mr = attn @ Mem fused with LSTM update
    gemm3k<<<1024, 256, 0, stream>>>(packed, pstride, MemT, gates, cell, out);

    if (!big) expand_attn<<<Bn, 256, 0, stream>>>(attn);
}

// Round 6
// 461.983 us; speedup vs baseline: 1.3416x; 1.3416x over previous
//
#include <hip/hip_runtime.h>
#include <hip/hip_bf16.h>
#include <math.h>

typedef __bf16 bf16_t;
typedef bf16_t bf16x8 __attribute__((ext_vector_type(8)));
typedef float  f32x4  __attribute__((ext_vector_type(4)));

static constexpr int Bn = 16384;
static constexpr int Hn = 512;

__device__ __forceinline__ float sigm(float x) { return 1.0f / (1.0f + __expf(-x)); }

typedef __attribute__((address_space(3))) void lds_void;
typedef const __attribute__((address_space(1))) void gl_void;

__device__ __forceinline__ void glds16(const void* g, void* l) {
    __builtin_amdgcn_global_load_lds((gl_void*)g, (lds_void*)l, 16, 0, 0);
}

// comb[B][1024] bf16 = [input | hidden]
__global__ void convert_comb(const float* __restrict__ inp, const float* __restrict__ hid,
                             bf16_t* __restrict__ comb)
{
    size_t t = (size_t)blockIdx.x * blockDim.x + threadIdx.x;
    size_t r = t >> 7;
    int c8 = (int)(t & 127);
    const float* src = (c8 < 64) ? (inp + r * 512 + c8 * 8) : (hid + r * 512 + (c8 - 64) * 8);
    float4 a = ((const float4*)src)[0];
    float4 b = ((const float4*)src)[1];
    bf16x8 o;
    o[0] = (bf16_t)a.x; o[1] = (bf16_t)a.y; o[2] = (bf16_t)a.z; o[3] = (bf16_t)a.w;
    o[4] = (bf16_t)b.x; o[5] = (bf16_t)b.y; o[6] = (bf16_t)b.z; o[7] = (bf16_t)b.w;
    *(bf16x8*)(comb + t * 8) = o;
}

// All three weight transposes in one launch.
__global__ void transpose_all(const float* __restrict__ Wg, bf16_t* __restrict__ WgT,
                              const float* __restrict__ Wa, bf16_t* __restrict__ WaT,
                              const float* __restrict__ Mem, bf16_t* __restrict__ MemT)
{
    __shared__ float tile[32][33];
    int b = blockIdx.x;
    const float* src; bf16_t* dst; int R, C, gx;
    if (b < 2048)      { src = Wg;  dst = WgT;  R = 1024; C = 2048; gx = 64; }
    else if (b < 4096) { b -= 2048; src = Wa;  dst = WaT;  R = 512;  C = 4096; gx = 128; }
    else               { b -= 4096; src = Mem; dst = MemT; R = 4096; C = 512;  gx = 16; }
    const int x0 = (b % gx) * 32, y0 = (b / gx) * 32;
    const int tx = threadIdx.x & 31, ty = threadIdx.x >> 5;
#pragma unroll
    for (int i = 0; i < 32; i += 8)
        tile[ty + i][tx] = src[(size_t)(y0 + ty + i) * C + x0 + tx];
    __syncthreads();
#pragma unroll
    for (int i = 0; i < 32; i += 8)
        dst[(size_t)(x0 + ty + i) * R + y0 + tx] = (bf16_t)tile[tx][ty + i];
}

// C[M,N] = epi(A @ Bt^T + bias). 128x256 tile, BK=64, 8 waves (2x4), 512 threads.
// LDS rows 128B = 8 x 16B slots, swizzle slot ^= (row&7); linear glds dest +
// inverse-swizzled source + swizzled ds_read (involution).
// EPI 0: activated gates -> bout stride 2048. EPI 1: bf16 logits -> bout stride ost.
template<int EPI>
__global__ __launch_bounds__(512)
void gemm_w8(const bf16_t* __restrict__ A, int lda,
             const bf16_t* __restrict__ Bt, int ldb,
             const float* __restrict__ bias, int K, int N,
             bf16_t* __restrict__ bout, int ost)
{
    __shared__ __align__(16) bf16_t sA[128 * 64];   // 16 KB
    __shared__ __align__(16) bf16_t sB[256 * 64];   // 32 KB

    const int tid = threadIdx.x, lane = tid & 63, wid = tid >> 6;
    const int wr = wid >> 2, wc = wid & 3;          // 2x4 waves

    const int nwg = gridDim.x;
    int bid = (blockIdx.x & 7) * (nwg >> 3) + (blockIdx.x >> 3);  // XCD swizzle
    const int cbn = N >> 8;
    const int row0 = (bid / cbn) * 128, col0 = (bid % cbn) * 256;

    f32x4 acc[4][4] = {};
    const int nk = K >> 6;
    const int l15 = lane & 15, kq = lane >> 4;

    for (int kt = 0; kt < nk; ++kt) {
        const int k0 = kt << 6;
        // ---- stage A: 16 chunks (2/wave), B: 32 chunks (4/wave); 1KB chunk = 8 rows
        {
            const int slot = (lane & 7) ^ (lane >> 3);
#pragma unroll
            for (int t = 0; t < 2; ++t) {
                const int c8 = wid * 2 + t;
                const int r = c8 * 8 + (lane >> 3);
                glds16(A + (size_t)(row0 + r) * lda + k0 + slot * 8, sA + c8 * 512);
            }
#pragma unroll
            for (int t = 0; t < 4; ++t) {
                const int c8 = wid * 4 + t;
                const int r = c8 * 8 + (lane >> 3);
                glds16(Bt + (size_t)(col0 + r) * ldb + k0 + slot * 8, sB + c8 * 512);
            }
        }
        __syncthreads();
#pragma unroll
        for (int ks = 0; ks < 2; ++ks) {
            bf16x8 af[4], bfr[4];
            const int slot = (ks * 4 + kq) ^ (l15 & 7);
#pragma unroll
            for (int j = 0; j < 4; ++j) {
                const int rb = wc * 64 + j * 16 + l15;
                bfr[j] = *(const bf16x8*)&sB[rb * 64 + slot * 8];
                const int ra = wr * 64 + j * 16 + l15;
                af[j] = *(const bf16x8*)&sA[ra * 64 + slot * 8];
            }
#pragma unroll
            for (int i = 0; i < 4; ++i)
#pragma unroll
                for (int j = 0; j < 4; ++j)
                    acc[i][j] = __builtin_amdgcn_mfma_f32_16x16x32_bf16(af[i], bfr[j], acc[i][j], 0, 0, 0);
        }
        __syncthreads();
    }

    const int lr = (lane >> 4) * 4, lc = lane & 15;
#pragma unroll
    for (int i = 0; i < 4; ++i) {
#pragma unroll
        for (int j = 0; j < 4; ++j) {
#pragma unroll
            for (int r = 0; r < 4; ++r) {
                const int grow = row0 + wr * 64 + i * 16 + lr + r;
                const int gcol = col0 + wc * 64 + j * 16 + lc;
                float v = acc[i][j][r] + bias[gcol];
                if constexpr (EPI == 0) {
                    const float a = ((gcol >> 9) == 2) ? tanhf(v) : sigm(v);
                    bout[(size_t)grow * 2048 + gcol] = (bf16_t)a;
                } else {
                    bout[(size_t)grow * ost + gcol] = (bf16_t)v;
                }
            }
        }
    }
}

// mr = attn_bf16 @ MemT^T fused with LSTM update. 64x256 tile, BK=64, 8 waves (2x4).
__global__ __launch_bounds__(512)
void gemm3k(const bf16_t* __restrict__ Ap, int astride,
            const bf16_t* __restrict__ MemT,
            const bf16_t* __restrict__ gates, const float* __restrict__ cell,
            float* __restrict__ fout)
{
    __shared__ __align__(16) bf16_t sA[64 * 64];    // 8 KB
    __shared__ __align__(16) bf16_t sB[256 * 64];   // 32 KB

    const int tid = threadIdx.x, lane = tid & 63, wid = tid >> 6;
    const int wr = wid >> 2, wc = wid & 3;

    int bid = (blockIdx.x & 7) * 64 + (blockIdx.x >> 3);   // 512 blocks
    const int row0 = (bid >> 1) * 64, col0 = (bid & 1) * 256;

    f32x4 acc[2][4] = {};
    const int l15 = lane & 15, kq = lane >> 4;

    for (int kt = 0; kt < 64; ++kt) {
        const int k0 = kt << 6;
        const int slot = (lane & 7) ^ (lane >> 3);
        {   // A: 8 chunks, 1/wave
            const int c8 = wid;
            const int r = c8 * 8 + (lane >> 3);
            glds16(Ap + (size_t)(row0 + r) * astride + k0 + slot * 8, sA + c8 * 512);
        }
#pragma unroll
        for (int t = 0; t < 4; ++t) {               // B: 32 chunks, 4/wave
            const int c8 = wid * 4 + t;
            const int r = c8 * 8 + (lane >> 3);
            glds16(MemT + (size_t)(col0 + r) * 4096 + k0 + slot * 8, sB + c8 * 512);
        }
        __syncthreads();
#pragma unroll
        for (int ks = 0; ks < 2; ++ks) {
            bf16x8 af[2], bfr[4];
            const int sl = (ks * 4 + kq) ^ (l15 & 7);
#pragma unroll
            for (int j = 0; j < 4; ++j) {
                const int rb = wc * 64 + j * 16 + l15;
                bfr[j] = *(const bf16x8*)&sB[rb * 64 + sl * 8];
            }
#pragma unroll
            for (int i = 0; i < 2; ++i) {
                const int ra = wr * 32 + i * 16 + l15;
                af[i] = *(const bf16x8*)&sA[ra * 64 + sl * 8];
            }
#pragma unroll
            for (int i = 0; i < 2; ++i)
#pragma unroll
                for (int j = 0; j < 4; ++j)
                    acc[i][j] = __builtin_amdgcn_mfma_f32_16x16x32_bf16(af[i], bfr[j], acc[i][j], 0, 0, 0);
        }
        __syncthreads();
    }

    const int lr = (lane >> 4) * 4, lc = lane & 15;
#pragma unroll
    for (int i = 0; i < 2; ++i) {
#pragma unroll
        for (int j = 0; j < 4; ++j) {
#pragma unroll
            for (int r = 0; r < 4; ++r) {
                const int grow = row0 + wr * 32 + i * 16 + lr + r;
                const int gcol = col0 + wc * 64 + j * 16 + lc;
                const float v = acc[i][j][r];
                const float ig = (float)gates[(size_t)grow * 2048 + gcol];
                const float fg = (float)gates[(size_t)grow * 2048 + 512 + gcol];
                const float cg = (float)gates[(size_t)grow * 2048 + 1024 + gcol];
                const float og = (float)gates[(size_t)grow * 2048 + 1536 + gcol];
                const float cv = cell[(size_t)grow * 512 + gcol];
                const float ncv = fg * cv + ig * cg + 0.1f * v;
                fout[(size_t)grow * 512 + gcol] = og * tanhf(ncv);
                fout[(size_t)Bn * Hn + (size_t)grow * 512 + gcol] = ncv;
            }
        }
    }
}

// Row softmax over packed bf16 logits (stride pstride). Writes bf16 attn back in
// place; if F32OUT also writes the full fp32 attn row to attnf32.
template<bool F32OUT>
__global__ void softmax_k(bf16_t* __restrict__ packed, int pstride, float* __restrict__ attnf32)
{
    const int row = blockIdx.x;
    bf16_t* lp = packed + (size_t)row * pstride;
    const int tid = threadIdx.x;

    float v[16];
    {
        bf16x8 h0 = ((const bf16x8*)lp)[tid];
        bf16x8 h1 = ((const bf16x8*)lp)[tid + 256];
#pragma unroll
        for (int k = 0; k < 8; ++k) { v[k] = (float)h0[k]; v[8 + k] = (float)h1[k]; }
    }
    float mx = v[0];
#pragma unroll
    for (int k = 1; k < 16; ++k) mx = fmaxf(mx, v[k]);
#pragma unroll
    for (int off = 32; off > 0; off >>= 1) mx = fmaxf(mx, __shfl_xor(mx, off));
    __shared__ float smx[4], ssm[4];
    if ((tid & 63) == 0) smx[tid >> 6] = mx;
    __syncthreads();
    mx = fmaxf(fmaxf(smx[0], smx[1]), fmaxf(smx[2], smx[3]));

    float sum = 0.0f;
#pragma unroll
    for (int k = 0; k < 16; ++k) { v[k] = __expf(v[k] - mx); sum += v[k]; }
#pragma unroll
    for (int off = 32; off > 0; off >>= 1) sum += __shfl_xor(sum, off);
    if ((tid & 63) == 0) ssm[tid >> 6] = sum;
    __syncthreads();
    sum = ssm[0] + ssm[1] + ssm[2] + ssm[3];

    const float inv = 1.0f / sum;
#pragma unroll
    for (int k = 0; k < 16; ++k) v[k] *= inv;

    bf16x8 o0, o1;
#pragma unroll
    for (int k = 0; k < 8; ++k) { o0[k] = (bf16_t)v[k]; o1[k] = (bf16_t)v[8 + k]; }
    ((bf16x8*)lp)[tid]       = o0;
    ((bf16x8*)lp)[tid + 256] = o1;

    if constexpr (F32OUT) {
        float* rp = attnf32 + (size_t)row * 4096;
        float4 a0 = { v[0], v[1], v[2], v[3] },   a1 = { v[4], v[5], v[6], v[7] };
        float4 a2 = { v[8], v[9], v[10], v[11] }, a3 = { v[12], v[13], v[14], v[15] };
        ((float4*)rp)[2 * tid]             = a0;
        ((float4*)rp)[2 * tid + 1]         = a1;
        ((float4*)rp)[2 * (tid + 256)]     = a2;
        ((float4*)rp)[2 * (tid + 256) + 1] = a3;
    }
}

// Expand packed bf16 attn row (first half) -> full fp32 row, in place (fallback).
__global__ void expand_attn(float* __restrict__ attn)
{
    const int row = blockIdx.x;
    float* rp = attn + (size_t)row * 4096;
    const int t = threadIdx.x;
    bf16x8 h0 = ((const bf16x8*)rp)[2 * t];
    bf16x8 h1 = ((const bf16x8*)rp)[2 * t + 1];
    __syncthreads();
    float4 o0 = { (float)h0[0], (float)h0[1], (float)h0[2], (float)h0[3] };
    float4 o1 = { (float)h0[4], (float)h0[5], (float)h0[6], (float)h0[7] };
    float4 o2 = { (float)h1[0], (float)h1[1], (float)h1[2], (float)h1[3] };
    float4 o3 = { (float)h1[4], (float)h1[5], (float)h1[6], (float)h1[7] };
    ((float4*)rp)[4 * t]     = o0;
    ((float4*)rp)[4 * t + 1] = o1;
    ((float4*)rp)[4 * t + 2] = o2;
    ((float4*)rp)[4 * t + 3] = o3;
}

extern "C" void kernel_launch(void* const* d_in, const int* in_sizes, int n_in,
                              void* d_out, int out_size, void* d_ws, size_t ws_size,
                              hipStream_t stream)
{
    const float* input  = (const float*)d_in[0];
    const float* hidden = (const float*)d_in[1];
    const float* cell   = (const float*)d_in[2];
    const float* Wg     = (const float*)d_in[3];
    const float* bg     = (const float*)d_in[4];
    const float* Wa     = (const float*)d_in[5];
    const float* ba     = (const float*)d_in[6];
    const float* Mem    = (const float*)d_in[7];

    float* out  = (float*)d_out;
    float* attn = out + 2ull * Bn * Hn;

    bf16_t* comb  = (bf16_t*)d_ws;                 // [B][1024]      33.5 MB
    bf16_t* WgT   = comb + (size_t)Bn * 1024;      // [2048][1024]    4.2
    bf16_t* WaT   = WgT + (size_t)2048 * 1024;     // [4096][512]     4.2
    bf16_t* MemT  = WaT + (size_t)4096 * 512;      // [512][4096]     4.2
    bf16_t* gates = MemT + (size_t)512 * 4096;     // [B][2048]      67.1
    bf16_t* pws   = gates + (size_t)Bn * 2048;     // [B][4096]     134.2 (big path)

    const size_t need_big = ((size_t)Bn * 1024 + 2048 * 1024 + 4096 * 512 + 512 * 4096
                             + (size_t)Bn * 2048 + (size_t)Bn * 4096) * sizeof(bf16_t);
    const bool big = ws_size >= need_big;
    bf16_t* packed = big ? pws : (bf16_t*)attn;
    const int pstride = big ? 4096 : 8192;

    convert_comb<<<8192, 256, 0, stream>>>(input, hidden, comb);
    transpose_all<<<6144, 256, 0, stream>>>(Wg, WgT, Wa, WaT, Mem, MemT);

    // gates = act([x|h] @ Wg + bg): 128x256 tiles, grid 128x8
    gemm_w8<0><<<1024, 512, 0, stream>>>(comb, 1024, WgT, 1024, bg, 1024, 2048, gates, 2048);
    // logits = h @ Wa + ba (packed bf16): grid 128x16
    gemm_w8<1><<<2048, 512, 0, stream>>>(comb + 512, 1024, WaT, 512, ba, 512, 4096,
                                         packed, pstride);

    if (big) softmax_k<true><<<Bn, 256, 0, stream>>>(packed, pstride, attn);
    else     softmax_k<false><<<Bn, 256, 0, stream>>>(packed, pstride, nullptr);

    // mr = attn @ Mem fused with LSTM update: 64x256 tiles, grid 256x2
    gemm3k<<<512, 512, 0, stream>>>(packed, pstride, MemT, gates, cell, out);

    if (!big) expand_attn<<<Bn, 256, 0, stream>>>(attn);
}